// Round 3
// baseline (75.938 us; speedup 1.0000x reference)
//
#include <hip/hip_runtime.h>

typedef float f32x4 __attribute__((ext_vector_type(4)));
typedef __bf16 bf16x8 __attribute__((ext_vector_type(8)));
typedef int i32x4 __attribute__((ext_vector_type(4)));
typedef unsigned short u16;
typedef unsigned int u32;

#define ALPHA 0.2f

__device__ __forceinline__ u16 f2bf(float x) {
    u32 u = __float_as_uint(x);
    u += 0x7FFFu + ((u >> 16) & 1u);   // round-to-nearest-even; inputs are finite
    return (u16)(u >> 16);
}

// ---------------------------------------------------------------------------
// K1: Wh = h @ W^T  (fp32 register-tiled), fused e_i/e_j, and bf16 Wh^T store.
// grid 256 blocks (64 rows each), 256 threads. Thread (tx,ty) owns 4 rows x 4 outs.
// ---------------------------------------------------------------------------
__global__ __launch_bounds__(256) void k_wh(
    const float* __restrict__ hsrc, const float* __restrict__ Wsrc,
    const float* __restrict__ asrc,
    u16* __restrict__ WhbT,          // [8][64][2048] bf16 (f-major, m contiguous)
    float* __restrict__ ei, float* __restrict__ ej)
{
    __shared__ float Wl[64][68];     // [k][o]
    __shared__ float hl[64][68];     // [k][r]
    __shared__ __align__(16) u16 tl[4096];  // 64x64 bf16 transpose buffer, swizzled

    const int tid = threadIdx.x;
    const int tx = tid & 15, ty = tid >> 4;
    const int R0 = blockIdx.x * 64;

    float acc[4][4] = {};

    for (int kc = 0; kc < 4; ++kc) {
        const int k0 = kc * 64;
        __syncthreads();
        #pragma unroll
        for (int p = 0; p < 4; ++p) {
            int idx = p * 1024 + tid * 4;
            int row = idx >> 6, k = idx & 63;
            float4 wv4 = *reinterpret_cast<const float4*>(&Wsrc[row * 256 + k0 + k]);
            Wl[k + 0][row] = wv4.x; Wl[k + 1][row] = wv4.y;
            Wl[k + 2][row] = wv4.z; Wl[k + 3][row] = wv4.w;
            float4 hv4 = *reinterpret_cast<const float4*>(&hsrc[(size_t)(R0 + row) * 256 + k0 + k]);
            hl[k + 0][row] = hv4.x; hl[k + 1][row] = hv4.y;
            hl[k + 2][row] = hv4.z; hl[k + 3][row] = hv4.w;
        }
        __syncthreads();
        #pragma unroll 4
        for (int k = 0; k < 64; ++k) {
            float4 hv = *reinterpret_cast<const float4*>(&hl[k][4 * ty]);
            float4 wv = *reinterpret_cast<const float4*>(&Wl[k][4 * tx]);
            float hr[4] = {hv.x, hv.y, hv.z, hv.w};
            float wc[4] = {wv.x, wv.y, wv.z, wv.w};
            #pragma unroll
            for (int i = 0; i < 4; ++i)
                #pragma unroll
                for (int j = 0; j < 4; ++j)
                    acc[i][j] = fmaf(hr[i], wc[j], acc[i][j]);
        }
    }

    // e_i / e_j: partial dot with a, reduce across the 16 tx lanes (in-wave).
    float4 av_i = *reinterpret_cast<const float4*>(&asrc[4 * tx]);
    float4 av_j = *reinterpret_cast<const float4*>(&asrc[64 + 4 * tx]);
    #pragma unroll
    for (int i = 0; i < 4; ++i) {
        float pi = acc[i][0]*av_i.x + acc[i][1]*av_i.y + acc[i][2]*av_i.z + acc[i][3]*av_i.w;
        float pj = acc[i][0]*av_j.x + acc[i][1]*av_j.y + acc[i][2]*av_j.z + acc[i][3]*av_j.w;
        #pragma unroll
        for (int off = 1; off < 16; off <<= 1) {
            pi += __shfl_xor(pi, off, 64);
            pj += __shfl_xor(pj, off, 64);
        }
        if (tx == 0) {
            ei[R0 + 4 * ty + i] = pi;
            ej[R0 + 4 * ty + i] = pj;
        }
    }

    // Transpose Wh tile to bf16 [o][r] via swizzled LDS, then coalesced store.
    #pragma unroll
    for (int i = 0; i < 4; ++i)
        #pragma unroll
        for (int j = 0; j < 4; ++j) {
            int row = 4 * tx + j;    // o
            int col = 4 * ty + i;    // r (local m)
            tl[(row * 64 + col) ^ ((row & 7) << 3)] = f2bf(acc[i][j]);
        }
    __syncthreads();
    {
        const int b = blockIdx.x >> 5;
        const int nloc = (blockIdx.x & 31) * 64;
        const int o = tid >> 2, rg = tid & 3;
        #pragma unroll
        for (int c = 0; c < 2; ++c) {
            int u = (o * 64 + rg * 16 + 8 * c) ^ ((o & 7) << 3);
            int4 v = *reinterpret_cast<const int4*>(&tl[u]);
            *reinterpret_cast<int4*>(&WhbT[(size_t)(b * 64 + o) * 2048 + nloc + rg * 16 + 8 * c]) = v;
        }
    }
}

// ---------------------------------------------------------------------------
// K3: fused masked softmax-attention. 512 blocks (b, 32-row tile), 4 waves,
// 2 blocks/CU so barriers of one block overlap loads of the other.
// Mj = max_m e_j is computed inline per block (8 KB, L2-resident).
// p = adj ? exp(lrelu(ei+ej) - M) : 0 (p<=1 by construction); bf16 MFMA
// p @ [Wh | ones] accumulates numerator AND denominator.
// ---------------------------------------------------------------------------
__global__ __launch_bounds__(256) void k_attn(
    const int* __restrict__ adj, const u16* __restrict__ WhbT,
    const float* __restrict__ ei_g, const float* __restrict__ ej_g,
    float* __restrict__ out)
{
    __shared__ __align__(16) u16 p_lds[32 * 64];   // [r][m] bf16, XOR-swizzled
    __shared__ __align__(16) u16 whT[80 * 64];     // [f][m] bf16 (+16 ones/zero rows)
    __shared__ float Mrow[32];
    __shared__ float eis[32];
    __shared__ float sden[32];
    __shared__ float red[4];

    const int tid  = threadIdx.x;
    const int lane = tid & 63;
    const int wid  = tid >> 6;
    const int b    = blockIdx.x >> 6;
    const int n0   = (blockIdx.x & 63) * 32;

    // ---- inline Mj = max_m e_j[b,m] ----
    {
        float4 v0 = *reinterpret_cast<const float4*>(&ej_g[b * 2048 + tid * 4]);
        float4 v1 = *reinterpret_cast<const float4*>(&ej_g[b * 2048 + 1024 + tid * 4]);
        float v = fmaxf(fmaxf(fmaxf(v0.x, v0.y), fmaxf(v0.z, v0.w)),
                        fmaxf(fmaxf(v1.x, v1.y), fmaxf(v1.z, v1.w)));
        #pragma unroll
        for (int off = 1; off < 64; off <<= 1) v = fmaxf(v, __shfl_xor(v, off, 64));
        if (lane == 0) red[wid] = v;
    }
    // ones column rows f=64..79 (f=64 is the denominator column, rest zero)
    {
        int row = 64 + (tid >> 4);
        int m = (tid & 15) * 4;
        u16 one = (row == 64) ? (u16)0x3F80 : (u16)0;
        int u = (row * 64 + m) ^ ((row & 7) << 3);
        whT[u + 0] = one; whT[u + 1] = one; whT[u + 2] = one; whT[u + 3] = one;
    }
    __syncthreads();
    const float Mjv = fmaxf(fmaxf(red[0], red[1]), fmaxf(red[2], red[3]));
    if (tid < 32) {
        float e = ei_g[b * 2048 + n0 + tid];
        eis[tid] = e;
        float x = e + Mjv;
        Mrow[tid] = fmaxf(x, ALPHA * x);   // lrelu(e_i + max_m e_j) >= any row score
    }

    const int mA  = (tid & 15) * 4;   // p-compute: m offset
    const int rA  = tid >> 4;         // p-compute: row base (0..15), rows rA, rA+16
    const int fW  = tid >> 2;         // Wh stage: f
    const int mgW = tid & 3;          // Wh stage: m-group

    const int* adjbase = adj + (size_t)(b * 2048 + n0) * 2048;
    const u16* wbase   = WhbT + (size_t)(b * 64) * 2048;

    i32x4 adjv[2]; float4 ejv; int4 wvv[2];
    auto LOADT = [&](int t) {
        const int m0 = t * 64;
        #pragma unroll
        for (int i = 0; i < 2; ++i)
            adjv[i] = __builtin_nontemporal_load(
                reinterpret_cast<const i32x4*>(&adjbase[(size_t)(rA + 16 * i) * 2048 + m0 + mA]));
        ejv = *reinterpret_cast<const float4*>(&ej_g[b * 2048 + m0 + mA]);
        #pragma unroll
        for (int c = 0; c < 2; ++c)
            wvv[c] = *reinterpret_cast<const int4*>(&wbase[(size_t)fW * 2048 + m0 + mgW * 16 + 8 * c]);
    };

    // MFMA split: rb = row-block (0/1), fbg = fb-group (0:{0,1,2} / 1:{3,4})
    const int rb  = wid & 1;
    const int fbg = wid >> 1;
    const int nfb = fbg ? 2 : 3;
    const int fb0 = fbg ? 3 : 0;
    f32x4 acc[3] = {};

    LOADT(0);
    __syncthreads();   // eis/Mrow/ones ready

    for (int t = 0; t < 32; ++t) {
        // ---- phase A: p tile + Wh tile into LDS ----
        #pragma unroll
        for (int i = 0; i < 2; ++i) {
            const int r = rA + 16 * i;
            const float eiv = eis[r];
            const float M = Mrow[r];
            const int am[4] = {adjv[i].x, adjv[i].y, adjv[i].z, adjv[i].w};
            const float ejs[4] = {ejv.x, ejv.y, ejv.z, ejv.w};
            u16 us[4];
            #pragma unroll
            for (int j = 0; j < 4; ++j) {
                float x = eiv + ejs[j];
                float lr = fmaxf(x, ALPHA * x);
                float p = __expf(lr - M);          // <= 1 by construction
                p = (am[j] != 0) ? p : 0.0f;
                us[j] = f2bf(p);
            }
            const int u = (r * 64 + mA) ^ ((r & 7) << 3);
            *reinterpret_cast<uint2*>(&p_lds[u]) =
                make_uint2((u32)us[0] | ((u32)us[1] << 16), (u32)us[2] | ((u32)us[3] << 16));
        }
        #pragma unroll
        for (int c = 0; c < 2; ++c) {
            const int u = (fW * 64 + mgW * 16 + 8 * c) ^ ((fW & 7) << 3);
            *reinterpret_cast<int4*>(&whT[u]) = wvv[c];
        }
        if (t < 31) LOADT(t + 1);   // prefetch next tile during MFMA phase
        __syncthreads();

        // ---- phase B: MFMA 32x80 += p(32x64) @ whT^T ----
        #pragma unroll
        for (int c = 0; c < 2; ++c) {
            const int row = 16 * rb + (lane & 15);
            const int kb = c * 32 + (lane >> 4) * 8;
            bf16x8 af = *reinterpret_cast<const bf16x8*>(&p_lds[(row * 64 + kb) ^ ((row & 7) << 3)]);
            #pragma unroll
            for (int q = 0; q < 3; ++q) {
                if (q < nfb) {
                    const int f = (fb0 + q) * 16 + (lane & 15);
                    bf16x8 bfr = *reinterpret_cast<const bf16x8*>(&whT[(f * 64 + kb) ^ ((f & 7) << 3)]);
                    acc[q] = __builtin_amdgcn_mfma_f32_16x16x32_bf16(af, bfr, acc[q], 0, 0, 0);
                }
            }
        }
        __syncthreads();
    }

    // ---- epilogue ----
    const int hi = lane >> 4, c0 = lane & 15;
    // denominator (fb=4, col f=64) lives in fbg==1 waves, acc[1], c0==0 lanes
    if (fbg == 1 && c0 == 0) {
        #pragma unroll
        for (int reg = 0; reg < 4; ++reg)
            sden[16 * rb + 4 * hi + reg] = acc[1][reg];
    }
    __syncthreads();
    #pragma unroll
    for (int reg = 0; reg < 4; ++reg) {
        const int r = 16 * rb + 4 * hi + reg;
        float sv = sden[r];
        float inv = (sv > 0.0f) ? 1.0f / sv : 0.0f;   // all-masked row -> 0 (nan_to_num)
        const int n = n0 + r;
        float* op = out + (size_t)(b * 2048 + n) * 64;
        #pragma unroll
        for (int q = 0; q < 3; ++q) {
            if (q < nfb && (fb0 + q) < 4) {
                op[(fb0 + q) * 16 + c0] = acc[q][reg] * inv;
            }
        }
    }
}

// ---------------------------------------------------------------------------
extern "C" void kernel_launch(void* const* d_in, const int* in_sizes, int n_in,
                              void* d_out, int out_size, void* d_ws, size_t ws_size,
                              hipStream_t stream)
{
    const float* h   = (const float*)d_in[0];   // [8,2048,256]
    const int*   adj = (const int*)d_in[1];     // [8,2048,2048]
    const float* W   = (const float*)d_in[2];   // [64,256]
    const float* a   = (const float*)d_in[3];   // [1,128]
    float* out = (float*)d_out;                  // [8,2048,64]

    u16*   WhbT = (u16*)d_ws;                               // 2 MB
    float* ei   = (float*)((char*)d_ws + 2 * 1024 * 1024);  // 64 KB
    float* ej   = ei + 16384;                               // 64 KB

    k_wh<<<dim3(256), dim3(256), 0, stream>>>(h, W, a, WhbT, ei, ej);
    k_attn<<<dim3(512), dim3(256), 0, stream>>>(adj, WhbT, ei, ej, out);
}

// Round 4
// 69.930 us; speedup vs baseline: 1.0859x; 1.0859x over previous
//
#include <hip/hip_runtime.h>

typedef float f32x4 __attribute__((ext_vector_type(4)));
typedef __bf16 bf16x8 __attribute__((ext_vector_type(8)));
typedef int i32x4 __attribute__((ext_vector_type(4)));
typedef unsigned short u16;
typedef unsigned int u32;

#define ALPHA 0.2f

__device__ __forceinline__ u16 f2bf(float x) {
    u32 u = __float_as_uint(x);
    u += 0x7FFFu + ((u >> 16) & 1u);   // round-to-nearest-even; inputs are finite
    return (u16)(u >> 16);
}

// ---------------------------------------------------------------------------
// K1: Wh = h @ W^T  (fp32 register-tiled), fused e_i/e_j, and bf16 Wh^T store.
// grid 256 blocks (64 rows each), 256 threads. Thread (tx,ty) owns 4 rows x 4 outs.
// ---------------------------------------------------------------------------
__global__ __launch_bounds__(256) void k_wh(
    const float* __restrict__ hsrc, const float* __restrict__ Wsrc,
    const float* __restrict__ asrc,
    u16* __restrict__ WhbT,          // [8][64][2048] bf16 (f-major, m contiguous)
    float* __restrict__ ei, float* __restrict__ ej)
{
    __shared__ float Wl[64][68];     // [k][o]
    __shared__ float hl[64][68];     // [k][r]
    __shared__ __align__(16) u16 tl[4096];  // 64x64 bf16 transpose buffer, swizzled

    const int tid = threadIdx.x;
    const int tx = tid & 15, ty = tid >> 4;
    const int R0 = blockIdx.x * 64;

    float acc[4][4] = {};

    for (int kc = 0; kc < 4; ++kc) {
        const int k0 = kc * 64;
        __syncthreads();
        #pragma unroll
        for (int p = 0; p < 4; ++p) {
            int idx = p * 1024 + tid * 4;
            int row = idx >> 6, k = idx & 63;
            float4 wv4 = *reinterpret_cast<const float4*>(&Wsrc[row * 256 + k0 + k]);
            Wl[k + 0][row] = wv4.x; Wl[k + 1][row] = wv4.y;
            Wl[k + 2][row] = wv4.z; Wl[k + 3][row] = wv4.w;
            float4 hv4 = *reinterpret_cast<const float4*>(&hsrc[(size_t)(R0 + row) * 256 + k0 + k]);
            hl[k + 0][row] = hv4.x; hl[k + 1][row] = hv4.y;
            hl[k + 2][row] = hv4.z; hl[k + 3][row] = hv4.w;
        }
        __syncthreads();
        #pragma unroll 4
        for (int k = 0; k < 64; ++k) {
            float4 hv = *reinterpret_cast<const float4*>(&hl[k][4 * ty]);
            float4 wv = *reinterpret_cast<const float4*>(&Wl[k][4 * tx]);
            float hr[4] = {hv.x, hv.y, hv.z, hv.w};
            float wc[4] = {wv.x, wv.y, wv.z, wv.w};
            #pragma unroll
            for (int i = 0; i < 4; ++i)
                #pragma unroll
                for (int j = 0; j < 4; ++j)
                    acc[i][j] = fmaf(hr[i], wc[j], acc[i][j]);
        }
    }

    // e_i / e_j: partial dot with a, reduce across the 16 tx lanes (in-wave).
    float4 av_i = *reinterpret_cast<const float4*>(&asrc[4 * tx]);
    float4 av_j = *reinterpret_cast<const float4*>(&asrc[64 + 4 * tx]);
    #pragma unroll
    for (int i = 0; i < 4; ++i) {
        float pi = acc[i][0]*av_i.x + acc[i][1]*av_i.y + acc[i][2]*av_i.z + acc[i][3]*av_i.w;
        float pj = acc[i][0]*av_j.x + acc[i][1]*av_j.y + acc[i][2]*av_j.z + acc[i][3]*av_j.w;
        #pragma unroll
        for (int off = 1; off < 16; off <<= 1) {
            pi += __shfl_xor(pi, off, 64);
            pj += __shfl_xor(pj, off, 64);
        }
        if (tx == 0) {
            ei[R0 + 4 * ty + i] = pi;
            ej[R0 + 4 * ty + i] = pj;
        }
    }

    // Transpose Wh tile to bf16 [o][r] via swizzled LDS, then coalesced store.
    #pragma unroll
    for (int i = 0; i < 4; ++i)
        #pragma unroll
        for (int j = 0; j < 4; ++j) {
            int row = 4 * tx + j;    // o
            int col = 4 * ty + i;    // r (local m)
            tl[(row * 64 + col) ^ ((row & 7) << 3)] = f2bf(acc[i][j]);
        }
    __syncthreads();
    {
        const int b = blockIdx.x >> 5;
        const int nloc = (blockIdx.x & 31) * 64;
        const int o = tid >> 2, rg = tid & 3;
        #pragma unroll
        for (int c = 0; c < 2; ++c) {
            int u = (o * 64 + rg * 16 + 8 * c) ^ ((o & 7) << 3);
            int4 v = *reinterpret_cast<const int4*>(&tl[u]);
            *reinterpret_cast<int4*>(&WhbT[(size_t)(b * 64 + o) * 2048 + nloc + rg * 16 + 8 * c]) = v;
        }
    }
}

// ---------------------------------------------------------------------------
// K3 (barrier-free): 512 blocks x 256 thr. Each wave owns 16 rows x 1024 m.
// p computed directly in MFMA A-fragment registers (lane: row=l&15,
// k-slot=(l>>4)*8+j); Wh B-fragments read straight from L2-resident WhbT;
// denominator = 5th MFMA vs in-register ones-fragment. adj prefetched 2
// iterations deep in registers; the ONLY barrier is the m-half combine.
// ---------------------------------------------------------------------------
__global__ __launch_bounds__(256) void k_attn(
    const int* __restrict__ adj, const u16* __restrict__ WhbT,
    const float* __restrict__ ei_g, const float* __restrict__ ej_g,
    float* __restrict__ out)
{
    __shared__ float accl[2][64][21];   // strip x lane x 20 acc floats (pad 21)

    const int tid   = threadIdx.x;
    const int lane  = tid & 63;
    const int wid   = tid >> 6;
    const int b     = blockIdx.x >> 6;   // 64 blocks per batch
    const int blk   = blockIdx.x & 63;
    const int strip = wid & 1;           // which 16-row strip
    const int half  = wid >> 1;          // which m-half (0..1023 / 1024..2047)
    const int n0    = blk * 32 + strip * 16;
    const int r     = lane & 15;         // A-fragment row / B-fragment f-offset
    const int ks    = lane >> 4;         // k-slot group

    const int*   adjp = adj  + (size_t)(b * 2048 + n0 + r) * 2048 + half * 1024 + ks * 8;
    const float* ejp  = ej_g + b * 2048 + half * 1024 + ks * 8;
    const u16*   whp  = WhbT + (size_t)(b * 64 + r) * 2048 + half * 1024 + ks * 8;

    i32x4 Aa0, Aa1, Ba0, Ba1;
    float4 Ae0, Ae1, Be0, Be1;
    bf16x8 Aw0, Aw1, Aw2, Aw3, Bw0, Bw1, Bw2, Bw3;

#define LOADS(t, a0,a1,e0,e1,w0,w1,w2,w3) { \
    const int mo_ = (t) * 32; \
    a0 = *reinterpret_cast<const i32x4*>(adjp + mo_); \
    a1 = *reinterpret_cast<const i32x4*>(adjp + mo_ + 4); \
    e0 = *reinterpret_cast<const float4*>(ejp + mo_); \
    e1 = *reinterpret_cast<const float4*>(ejp + mo_ + 4); \
    w0 = *reinterpret_cast<const bf16x8*>(whp + mo_); \
    w1 = *reinterpret_cast<const bf16x8*>(whp + 32768 + mo_); \
    w2 = *reinterpret_cast<const bf16x8*>(whp + 65536 + mo_); \
    w3 = *reinterpret_cast<const bf16x8*>(whp + 98304 + mo_); }

    LOADS(0, Aa0,Aa1,Ae0,Ae1,Aw0,Aw1,Aw2,Aw3);
    LOADS(1, Ba0,Ba1,Be0,Be1,Bw0,Bw1,Bw2,Bw3);

    // Mj = max_m e_j[b,m]  (8 KB, L2-resident; overlaps the loads above)
    float mj = -1e30f;
    #pragma unroll
    for (int i = 0; i < 8; ++i) {
        float4 v = *reinterpret_cast<const float4*>(&ej_g[b * 2048 + (i * 64 + lane) * 4]);
        mj = fmaxf(mj, fmaxf(fmaxf(v.x, v.y), fmaxf(v.z, v.w)));
    }
    #pragma unroll
    for (int off = 1; off < 64; off <<= 1) mj = fmaxf(mj, __shfl_xor(mj, off, 64));

    const float eiv = ei_g[b * 2048 + n0 + r];
    const float xM  = eiv + mj;
    const float M   = fmaxf(xM, ALPHA * xM);   // lrelu(e_i + max e_j) >= row max

    bf16x8 bones;   // ones-fragment: B[n=0][k]=1 -> denominator column
    {
        const float o = (r == 0) ? 1.0f : 0.0f;
        #pragma unroll
        for (int j = 0; j < 8; ++j) bones[j] = (__bf16)o;
    }

    f32x4 acc0 = {}, acc1 = {}, acc2 = {}, acc3 = {}, acc4 = {};

#define PVAL(av, ev, dst) { \
    float e_ = eiv + (ev); \
    float lr_ = fmaxf(e_, ALPHA * e_); \
    float p_ = __expf(lr_ - M); \
    dst = (__bf16)(((av) != 0) ? p_ : 0.0f); }

#define PSTEP(a0,a1,e0,e1,w0,w1,w2,w3) { \
    bf16x8 af; \
    PVAL(a0.x, e0.x, af[0]); PVAL(a0.y, e0.y, af[1]); \
    PVAL(a0.z, e0.z, af[2]); PVAL(a0.w, e0.w, af[3]); \
    PVAL(a1.x, e1.x, af[4]); PVAL(a1.y, e1.y, af[5]); \
    PVAL(a1.z, e1.z, af[6]); PVAL(a1.w, e1.w, af[7]); \
    acc0 = __builtin_amdgcn_mfma_f32_16x16x32_bf16(af, w0, acc0, 0, 0, 0); \
    acc1 = __builtin_amdgcn_mfma_f32_16x16x32_bf16(af, w1, acc1, 0, 0, 0); \
    acc2 = __builtin_amdgcn_mfma_f32_16x16x32_bf16(af, w2, acc2, 0, 0, 0); \
    acc3 = __builtin_amdgcn_mfma_f32_16x16x32_bf16(af, w3, acc3, 0, 0, 0); \
    acc4 = __builtin_amdgcn_mfma_f32_16x16x32_bf16(af, bones, acc4, 0, 0, 0); }

    // 32 m-steps of K=32, unrolled x2 with 2-deep register prefetch.
    for (int k = 0; k < 15; ++k) {
        const int t = 2 * k;
        PSTEP(Aa0,Aa1,Ae0,Ae1,Aw0,Aw1,Aw2,Aw3);
        LOADS(t + 2, Aa0,Aa1,Ae0,Ae1,Aw0,Aw1,Aw2,Aw3);
        PSTEP(Ba0,Ba1,Be0,Be1,Bw0,Bw1,Bw2,Bw3);
        LOADS(t + 3, Ba0,Ba1,Be0,Be1,Bw0,Bw1,Bw2,Bw3);
    }
    PSTEP(Aa0,Aa1,Ae0,Ae1,Aw0,Aw1,Aw2,Aw3);
    PSTEP(Ba0,Ba1,Be0,Be1,Bw0,Bw1,Bw2,Bw3);

#undef LOADS
#undef PSTEP
#undef PVAL

    // ---- combine m-halves (single barrier) + normalize + store ----
    if (half == 1) {
        #pragma unroll
        for (int q = 0; q < 4; ++q) {
            accl[strip][lane][q]      = acc0[q];
            accl[strip][lane][4 + q]  = acc1[q];
            accl[strip][lane][8 + q]  = acc2[q];
            accl[strip][lane][12 + q] = acc3[q];
            accl[strip][lane][16 + q] = acc4[q];
        }
    }
    __syncthreads();
    if (half == 0) {
        #pragma unroll
        for (int q = 0; q < 4; ++q) {
            acc0[q] += accl[strip][lane][q];
            acc1[q] += accl[strip][lane][4 + q];
            acc2[q] += accl[strip][lane][8 + q];
            acc3[q] += accl[strip][lane][12 + q];
            acc4[q] += accl[strip][lane][16 + q];
        }
        #pragma unroll
        for (int q = 0; q < 4; ++q) {
            float d   = __shfl(acc4[q], lane & 48, 64);   // den in col-0 lanes
            float inv = (d > 0.0f) ? 1.0f / d : 0.0f;     // all-masked row -> 0
            const int n = n0 + ks * 4 + q;
            float* op = out + (size_t)(b * 2048 + n) * 64 + r;
            op[0]  = acc0[q] * inv;
            op[16] = acc1[q] * inv;
            op[32] = acc2[q] * inv;
            op[48] = acc3[q] * inv;
        }
    }
}

// ---------------------------------------------------------------------------
extern "C" void kernel_launch(void* const* d_in, const int* in_sizes, int n_in,
                              void* d_out, int out_size, void* d_ws, size_t ws_size,
                              hipStream_t stream)
{
    const float* h   = (const float*)d_in[0];   // [8,2048,256]
    const int*   adj = (const int*)d_in[1];     // [8,2048,2048]
    const float* W   = (const float*)d_in[2];   // [64,256]
    const float* a   = (const float*)d_in[3];   // [1,128]
    float* out = (float*)d_out;                  // [8,2048,64]

    u16*   WhbT = (u16*)d_ws;                               // 2 MB
    float* ei   = (float*)((char*)d_ws + 2 * 1024 * 1024);  // 64 KB
    float* ej   = ei + 16384;                               // 64 KB

    k_wh<<<dim3(256), dim3(256), 0, stream>>>(h, W, a, WhbT, ei, ej);
    k_attn<<<dim3(512), dim3(256), 0, stream>>>(adj, WhbT, ei, ej, out);
}